// Round 1
// baseline (103.202 us; speedup 1.0000x reference)
//
#include <hip/hip_runtime.h>

#define BLK 256

// ---------------------------------------------------------------------------
// Distance reduction: d2_out[item] += sum over chunk of (f - M[item])^2
// grid = (blocks_per_item, 10). n4 = float4 count per item.
// ---------------------------------------------------------------------------
__global__ void dist_kernel(const float* __restrict__ f, const float* __restrict__ M,
                            float* __restrict__ d2_out, int n4) {
    const int item = blockIdx.y;
    const float4* __restrict__ f4 = (const float4*)f;
    const float4* __restrict__ m4 = (const float4*)M + (size_t)item * n4;

    float acc = 0.f;
    for (int i = blockIdx.x * blockDim.x + threadIdx.x; i < n4;
         i += gridDim.x * blockDim.x) {
        float4 a = f4[i];
        float4 b = m4[i];
        float dx = a.x - b.x, dy = a.y - b.y, dz = a.z - b.z, dw = a.w - b.w;
        acc += dx * dx + dy * dy + dz * dz + dw * dw;
    }

    // wave64 butterfly reduce
    #pragma unroll
    for (int off = 32; off > 0; off >>= 1) acc += __shfl_down(acc, off);

    __shared__ float s[BLK / 64];
    const int lane = threadIdx.x & 63;
    const int wv   = threadIdx.x >> 6;
    if (lane == 0) s[wv] = acc;
    __syncthreads();
    if (threadIdx.x == 0) {
        float t = 0.f;
        #pragma unroll
        for (int w = 0; w < BLK / 64; ++w) t += s[w];
        atomicAdd(&d2_out[item], t);
    }
}

// ---------------------------------------------------------------------------
// total[i] = sqrt(d2[0*10+i]) + sqrt(d2[1*10+i]) + sqrt(d2[2*10+i]); argmin.
// Strict < with ascending i == jnp.argmin first-min tie behavior.
// ---------------------------------------------------------------------------
__global__ void argmin_kernel(const float* __restrict__ d2, int* __restrict__ idx_out) {
    if (threadIdx.x == 0 && blockIdx.x == 0) {
        float best = 3.4e38f;
        int bi = 0;
        for (int i = 0; i < 10; ++i) {
            float t = sqrtf(d2[i]) + sqrtf(d2[10 + i]) + sqrtf(d2[20 + i]);
            if (t < best) { best = t; bi = i; }
        }
        *idx_out = bi;
    }
}

// ---------------------------------------------------------------------------
// Gather + concat for one scale.
// CI[b, 0:C]  = feature[b]   (first n4 float4 work items)
// CI[b, C:2C] = M[idx][b]    (second n4 work items; also written to mi)
// sh = log2(per-batch float4 count S4); n4 = 8*S4.
// ---------------------------------------------------------------------------
__global__ void gather_kernel(const float* __restrict__ f, const float* __restrict__ M,
                              const int* __restrict__ idx_ptr,
                              float* __restrict__ CI, float* __restrict__ mi,
                              int sh, int n4) {
    const int idx = *idx_ptr;
    const float4* __restrict__ f4 = (const float4*)f;
    const float4* __restrict__ m4 = (const float4*)M + (size_t)idx * n4;
    float4* __restrict__ ci4 = (float4*)CI;
    float4* __restrict__ mi4 = (float4*)mi;
    const int S4 = 1 << sh;
    const int mask = S4 - 1;

    for (int i = blockIdx.x * blockDim.x + threadIdx.x; i < 2 * n4;
         i += gridDim.x * blockDim.x) {
        if (i < n4) {
            int b = i >> sh, r = i & mask;
            ci4[((size_t)b << (sh + 1)) + r] = f4[i];
        } else {
            int j = i - n4;
            int b = j >> sh, r = j & mask;
            float4 v = m4[j];
            ci4[((size_t)b << (sh + 1)) + S4 + r] = v;
            mi4[j] = v;
        }
    }
}

extern "C" void kernel_launch(void* const* d_in, const int* in_sizes, int n_in,
                              void* d_out, int out_size, void* d_ws, size_t ws_size,
                              hipStream_t stream) {
    const float* f1 = (const float*)d_in[0];  // (8,64,64,64)   = 2097152
    const float* f2 = (const float*)d_in[1];  // (8,128,32,32)  = 1048576
    const float* f3 = (const float*)d_in[2];  // (8,256,16,16)  = 524288
    const float* M1 = (const float*)d_in[3];  // (10, f1 shape)
    const float* M2 = (const float*)d_in[4];
    const float* M3 = (const float*)d_in[5];
    float* out = (float*)d_out;

    // Workspace: d2[30] floats ([scale*10 + item]), int idx at byte 128.
    float* d2 = (float*)d_ws;
    int* idxp = (int*)((char*)d_ws + 128);
    hipMemsetAsync(d_ws, 0, 132, stream);  // zero accumulators (ws is poisoned)

    // ---- phase 1: distances -------------------------------------------------
    auto launch_dist = [&](const float* f, const float* M, float* d2s, int elems) {
        int n4 = elems >> 2;
        int bpi = (n4 + BLK * 8 - 1) / (BLK * 8);  // ~8 float4 / thread
        dim3 grid(bpi, 10);
        dist_kernel<<<grid, BLK, 0, stream>>>(f, M, d2s, n4);
    };
    launch_dist(f1, M1, d2 + 0,  2097152);
    launch_dist(f2, M2, d2 + 10, 1048576);
    launch_dist(f3, M3, d2 + 20, 524288);

    // ---- phase 2: argmin ----------------------------------------------------
    argmin_kernel<<<1, 64, 0, stream>>>(d2, idxp);

    // ---- phase 3: gather + concat -------------------------------------------
    // Output flat layout (fp32 elements):
    //   CI1 @ 0         (8,128,64,64) = 4194304
    //   CI2 @ 4194304   (8,256,32,32) = 2097152
    //   CI3 @ 6291456   (8,512,16,16) = 1048576
    //   mi1 @ 7340032   (8,64,64,64)  = 2097152
    //   mi2 @ 9437184   (8,128,32,32) = 1048576
    //   mi3 @ 10485760  (8,256,16,16) = 524288
    auto launch_gather = [&](const float* f, const float* M, float* CI, float* mi,
                             int S /* per-batch elems of feature */) {
        int S4 = S >> 2;
        int sh = __builtin_ctz(S4);
        int n4 = 8 * S4;
        int total = 2 * n4;
        int blocks = (total + BLK - 1) / BLK;
        if (blocks > 2048) blocks = 2048;
        gather_kernel<<<blocks, BLK, 0, stream>>>(f, M, idxp, CI, mi, sh, n4);
    };
    launch_gather(f1, M1, out + 0,       out + 7340032,  262144);  // 64*64*64
    launch_gather(f2, M2, out + 4194304, out + 9437184,  131072);  // 128*32*32
    launch_gather(f3, M3, out + 6291456, out + 10485760, 65536);   // 256*16*16
}

// Round 2
// 54.463 us; speedup vs baseline: 1.8949x; 1.8949x over previous
//
#include <hip/hip_runtime.h>

#define BLK 256
#define MAXB 512   // partial slots per (scale,item) pair

// ---------------------------------------------------------------------------
// Fused distance kernel. grid = (MAXB, 30). pair = scale*10 + item.
// Each thread handles exactly 4 float4 pairs (8 independent loads in flight).
// Per-block partial sum -> partials[pair*MAXB + blockIdx.x] (deterministic).
// Per-scale float4 counts: 524288 / 262144 / 131072 -> nblocks 512/256/128.
// ---------------------------------------------------------------------------
__global__ void dist_kernel(const float* __restrict__ f1, const float* __restrict__ M1,
                            const float* __restrict__ f2, const float* __restrict__ M2,
                            const float* __restrict__ f3, const float* __restrict__ M3,
                            float* __restrict__ partials) {
    const int pair  = blockIdx.y;
    const int scale = pair >= 20 ? 2 : (pair >= 10 ? 1 : 0);
    const int item  = pair - scale * 10;
    const float* f; const float* M; int n4;
    if (scale == 0)      { f = f1; M = M1; n4 = 524288; }
    else if (scale == 1) { f = f2; M = M2; n4 = 262144; }
    else                 { f = f3; M = M3; n4 = 131072; }
    const int nblocks = n4 >> 10;        // n4 / (BLK*4)
    if ((int)blockIdx.x >= nblocks) return;

    const float4* __restrict__ f4 = (const float4*)f;
    const float4* __restrict__ m4 = (const float4*)M + (size_t)item * n4;
    const int tid = blockIdx.x * BLK + threadIdx.x;
    const int S   = nblocks * BLK;

    float4 a0 = f4[tid];
    float4 b0 = m4[tid];
    float4 a1 = f4[tid + S];
    float4 b1 = m4[tid + S];
    float4 a2 = f4[tid + 2 * S];
    float4 b2 = m4[tid + 2 * S];
    float4 a3 = f4[tid + 3 * S];
    float4 b3 = m4[tid + 3 * S];

    float acc = 0.f;
    {
        float dx, dy, dz, dw;
        dx = a0.x - b0.x; dy = a0.y - b0.y; dz = a0.z - b0.z; dw = a0.w - b0.w;
        acc += dx * dx + dy * dy + dz * dz + dw * dw;
        dx = a1.x - b1.x; dy = a1.y - b1.y; dz = a1.z - b1.z; dw = a1.w - b1.w;
        acc += dx * dx + dy * dy + dz * dz + dw * dw;
        dx = a2.x - b2.x; dy = a2.y - b2.y; dz = a2.z - b2.z; dw = a2.w - b2.w;
        acc += dx * dx + dy * dy + dz * dz + dw * dw;
        dx = a3.x - b3.x; dy = a3.y - b3.y; dz = a3.z - b3.z; dw = a3.w - b3.w;
        acc += dx * dx + dy * dy + dz * dz + dw * dw;
    }

    #pragma unroll
    for (int off = 32; off > 0; off >>= 1) acc += __shfl_down(acc, off);

    __shared__ float s[BLK / 64];
    if ((threadIdx.x & 63) == 0) s[threadIdx.x >> 6] = acc;
    __syncthreads();
    if (threadIdx.x == 0)
        partials[pair * MAXB + blockIdx.x] = s[0] + s[1] + s[2] + s[3];
}

// ---------------------------------------------------------------------------
// Reduce partials + argmin. 1 block x 256 threads. Wave w handles pairs
// w, w+4, ... Each pair sums its valid slot count (512 >> scale).
// ---------------------------------------------------------------------------
__global__ void reduce_argmin_kernel(const float* __restrict__ partials,
                                     int* __restrict__ idx_out) {
    __shared__ float tot[30];
    const int wv = threadIdx.x >> 6, lane = threadIdx.x & 63;
    for (int p = wv; p < 30; p += 4) {
        const int scale = p >= 20 ? 2 : (p >= 10 ? 1 : 0);
        const int nb = MAXB >> scale;
        float s = 0.f;
        for (int i = lane; i < nb; i += 64) s += partials[p * MAXB + i];
        #pragma unroll
        for (int off = 32; off > 0; off >>= 1) s += __shfl_down(s, off);
        if (lane == 0) tot[p] = s;
    }
    __syncthreads();
    if (threadIdx.x == 0) {
        float best = 3.4e38f; int bi = 0;
        for (int i = 0; i < 10; ++i) {
            float t = sqrtf(tot[i]) + sqrtf(tot[10 + i]) + sqrtf(tot[20 + i]);
            if (t < best) { best = t; bi = i; }
        }
        *idx_out = bi;
    }
}

// ---------------------------------------------------------------------------
// Fused gather+concat. grid = (2048, 3). Thread gid < n4 copies feature
// float4 gid -> CI first half and M[idx] float4 gid -> CI second half + mi.
// ---------------------------------------------------------------------------
__global__ void gather_kernel(const float* __restrict__ f1, const float* __restrict__ M1,
                              const float* __restrict__ f2, const float* __restrict__ M2,
                              const float* __restrict__ f3, const float* __restrict__ M3,
                              const int* __restrict__ idx_ptr, float* __restrict__ out) {
    const int s = blockIdx.y;
    const float* f; const float* M; int n4, sh; float* CI; float* mi;
    if (s == 0)      { f = f1; M = M1; n4 = 524288; sh = 16; CI = out;           mi = out + 7340032;  }
    else if (s == 1) { f = f2; M = M2; n4 = 262144; sh = 15; CI = out + 4194304; mi = out + 9437184;  }
    else             { f = f3; M = M3; n4 = 131072; sh = 14; CI = out + 6291456; mi = out + 10485760; }
    const int gid = blockIdx.x * BLK + threadIdx.x;
    if (gid >= n4) return;
    const int idx = *idx_ptr;

    const float4* __restrict__ f4 = (const float4*)f;
    const float4* __restrict__ m4 = (const float4*)M + (size_t)idx * n4;
    float4* __restrict__ ci4 = (float4*)CI;
    float4* __restrict__ mi4 = (float4*)mi;

    const int S4 = 1 << sh, mask = S4 - 1;
    const int b = gid >> sh, r = gid & mask;
    float4 va = f4[gid];
    float4 vb = m4[gid];
    const size_t cbase = ((size_t)b << (sh + 1)) + r;
    ci4[cbase]      = va;
    ci4[cbase + S4] = vb;
    mi4[gid]        = vb;
}

extern "C" void kernel_launch(void* const* d_in, const int* in_sizes, int n_in,
                              void* d_out, int out_size, void* d_ws, size_t ws_size,
                              hipStream_t stream) {
    const float* f1 = (const float*)d_in[0];  // (8,64,64,64)   = 2097152 fp32
    const float* f2 = (const float*)d_in[1];  // (8,128,32,32)  = 1048576
    const float* f3 = (const float*)d_in[2];  // (8,256,16,16)  = 524288
    const float* M1 = (const float*)d_in[3];
    const float* M2 = (const float*)d_in[4];
    const float* M3 = (const float*)d_in[5];
    float* out = (float*)d_out;

    // Output flat layout (fp32 elements):
    //   CI1 @ 0         (8,128,64,64) = 4194304
    //   CI2 @ 4194304   (8,256,32,32) = 2097152
    //   CI3 @ 6291456   (8,512,16,16) = 1048576
    //   mi1 @ 7340032   (8,64,64,64)  = 2097152
    //   mi2 @ 9437184   (8,128,32,32) = 1048576
    //   mi3 @ 10485760  (8,256,16,16) = 524288
    //
    // Scratch: partials (30*512 fp32 = 61.4 KB) live in the mi3 region of
    // d_out (written by dist, read by reducer, then fully overwritten by the
    // gather phase) -> no assumption on ws_size beyond 4 bytes for idx.
    float* partials = out + 10485760;
    int* idxp = (int*)d_ws;

    dist_kernel<<<dim3(MAXB, 30), BLK, 0, stream>>>(f1, M1, f2, M2, f3, M3, partials);
    reduce_argmin_kernel<<<1, BLK, 0, stream>>>(partials, idxp);
    gather_kernel<<<dim3(2048, 3), BLK, 0, stream>>>(f1, M1, f2, M2, f3, M3, idxp, out);
}